// Round 14
// baseline (51.297 us; speedup 1.0000x reference)
//
#include <hip/hip_runtime.h>
#include <hip/hip_bf16.h>

// out[m,u] = sum_t x[m,t] * W_eff[u,t] + b_eff[u]      (m = 32*512 rows)
//   W_eff = Ws + (Wt - Ws) @ A   (A = causal window-mean, window 25)
// Round-14: cross-block phase overlap WITHOUT the known cliffs.
//   Block = BM=64 x N-half(384u) x K-half(384 cols in LDS at a time).
//   LDS 64x396 bf16 = 50.7 KB -> 2 blocks/CU (16 waves/CU, 4/SIMD).
//   W traffic stays 289 MB L2 (BM=64 preserved); acc 4x3=48 AGPR + ring 24
//   -> ~123 regs <= 128 cap (r10's proven register recipe, not r7's).
//   Phases: stage0 / K0(12) / stage1 / K1(11) / epilogue, 3 barriers;
//   co-resident blocks at different phases overlap HBM vs L2 vs MFMA.

#define Tdim  720
#define KP    736      // padded K; Wb zero-filled for k>=720
#define WROWS 768      // padded u-rows of Wb (zero rows >=720)
#define BM    64
#define KH    384      // K-half width staged in LDS (half 1: 352 valid + 16 pad)
#define KHPAD 396      // LDS row stride elems: 198 dw %32=6, gcd 2 -> ~2-way

using bf16x8 = __attribute__((ext_vector_type(8))) __bf16;
using f32x4  = __attribute__((ext_vector_type(4))) float;

__global__ void fold_w_kernel(const float* __restrict__ tw,
                              const float* __restrict__ tb,
                              const float* __restrict__ sw,
                              const float* __restrict__ sb,
                              __bf16* __restrict__ Wb,
                              float* __restrict__ beff) {
  int idx = blockIdx.x * 256 + threadIdx.x;
  if (idx >= WROWS * KP) return;
  int u = idx / KP;
  int i = idx - u * KP;
  float w = 0.0f;
  if (u < Tdim && i < Tdim) {
    const float* twr = tw + (size_t)u * Tdim;
    const float* swr = sw + (size_t)u * Tdim;
    int tend = (i + 25 < Tdim) ? (i + 25) : Tdim;
    float acc = 0.0f;
    if (i >= 24) {
      #pragma unroll 5
      for (int t = i; t < tend; ++t) acc += twr[t] - swr[t];
      acc *= 0.04f;
    } else {
      for (int t = i; t < tend; ++t) {
        float c = (t >= 24) ? 0.04f : 1.0f / (float)(t + 1);
        acc += (twr[t] - swr[t]) * c;
      }
    }
    w = swr[i] + acc;
  }
  Wb[idx] = (__bf16)w;
  if (i == 0 && u < Tdim) beff[u] = tb[u] + sb[u];
}

__global__ __launch_bounds__(512, 4)
void dlinear_gemm(const float* __restrict__ x,
                  const __bf16* __restrict__ Wb,
                  const float* __restrict__ beff,
                  float* __restrict__ out) {
  __shared__ __bf16 As[BM * KHPAD];   // 50688 B -> 2 blocks/CU

  const int tid  = threadIdx.x;
  const int lane = tid & 63;
  const int wid  = tid >> 6;          // 0..7
  const int lg = lane >> 4, lr = lane & 15;

  const int mblk  = blockIdx.x >> 1;  // 0..255
  const int nhalf = blockIdx.x & 1;
  const int m0 = mblk * BM;
  const int u0 = nhalf * 384 + wid * 48;   // wave owns 48 u-cols

  // ---- staging macro: half H -> As (64 rows x KH cols, bf16)
  // 3072 8-f32 units / 512 thr = 6 each. Half 1: col8<42 valid (abs<=719),
  // col8 42..43 -> abs 720..735 = zero pad, col8>=44 never read (K1 = 11 steps).
#define STAGE_HALF(H)                                                          \
  {                                                                            \
    _Pragma("unroll")                                                          \
    for (int c = 0; c < 6; ++c) {                                              \
      int idx  = tid + 512 * c;                                                \
      int row  = idx / 48;                                                     \
      int col8 = idx - row * 48;                                               \
      if ((H) == 0 || col8 < 42) {                                             \
        const float* p = x + (size_t)(m0 + row) * Tdim + (H) * KH + col8 * 8;  \
        f32x4 a0 = ((const f32x4*)p)[0];                                       \
        f32x4 a1 = ((const f32x4*)p)[1];                                       \
        bf16x8 v;                                                              \
        _Pragma("unroll")                                                      \
        for (int j = 0; j < 4; ++j) {                                          \
          v[j] = (__bf16)a0[j]; v[j + 4] = (__bf16)a1[j];                      \
        }                                                                      \
        *(bf16x8*)(&As[row * KHPAD + col8 * 8]) = v;                           \
      } else if (col8 < 44) {                                                  \
        bf16x8 v;                                                              \
        _Pragma("unroll")                                                      \
        for (int j = 0; j < 8; ++j) v[j] = (__bf16)0.0f;                       \
        *(bf16x8*)(&As[row * KHPAD + col8 * 8]) = v;                           \
      }                                                                        \
    }                                                                          \
  }

  // ---- W stream pointers: frag ni -> row u0+ni*16+lr, 16B chunk lg
  const __bf16* wp[3];
  #pragma unroll
  for (int ni = 0; ni < 3; ++ni)
    wp[ni] = Wb + (size_t)(u0 + ni * 16 + lr) * KP + lg * 8;

  int arofs[4];
  #pragma unroll
  for (int mi = 0; mi < 4; ++mi) arofs[mi] = (mi * 16 + lr) * KHPAD + lg * 8;

  f32x4 acc[4][3];
  #pragma unroll
  for (int mi = 0; mi < 4; ++mi)
    #pragma unroll
    for (int ni = 0; ni < 3; ++ni) {
      f32x4 z; z[0] = 0.f; z[1] = 0.f; z[2] = 0.f; z[3] = 0.f;
      acc[mi][ni] = z;
    }

  bf16x8 sA[3], sB[3];                // depth-1 W ring, named slots

  // KSTEP: compute step T from CUR; optionally issue T+1 into NXT.
#define KSTEP(T, CUR, NXT, DO_LOAD, HOFF)                                      \
  {                                                                            \
    if (DO_LOAD) {                                                             \
      _Pragma("unroll")                                                        \
      for (int ni = 0; ni < 3; ++ni)                                           \
        NXT[ni] = *(const bf16x8*)(wp[ni] + (HOFF) + ((T) + 1) * 32);          \
    }                                                                          \
    bf16x8 av[4];                                                              \
    _Pragma("unroll")                                                          \
    for (int mi = 0; mi < 4; ++mi)                                             \
      av[mi] = *(const bf16x8*)(&As[arofs[mi] + (T) * 32]);                    \
    _Pragma("unroll")                                                          \
    for (int mi = 0; mi < 4; ++mi)                                             \
      _Pragma("unroll")                                                        \
      for (int ni = 0; ni < 3; ++ni)                                           \
        acc[mi][ni] = __builtin_amdgcn_mfma_f32_16x16x32_bf16(av[mi],          \
                        CUR[ni], acc[mi][ni], 0, 0, 0);                        \
  }

  // ================= half 0: cols 0..383, 12 K-steps =================
  STAGE_HALF(0)
  __syncthreads();
  #pragma unroll
  for (int ni = 0; ni < 3; ++ni) sA[ni] = *(const bf16x8*)(wp[ni]);
  KSTEP(0,  sA, sB, true,  0)
  KSTEP(1,  sB, sA, true,  0)
  KSTEP(2,  sA, sB, true,  0)
  KSTEP(3,  sB, sA, true,  0)
  KSTEP(4,  sA, sB, true,  0)
  KSTEP(5,  sB, sA, true,  0)
  KSTEP(6,  sA, sB, true,  0)
  KSTEP(7,  sB, sA, true,  0)
  KSTEP(8,  sA, sB, true,  0)
  KSTEP(9,  sB, sA, true,  0)
  KSTEP(10, sA, sB, true,  0)
  KSTEP(11, sB, sA, false, 0)
  __syncthreads();                    // all reads of As done before restage

  // ================= half 1: cols 384..735, 11 K-steps ================
  STAGE_HALF(1)
  __syncthreads();
  #pragma unroll
  for (int ni = 0; ni < 3; ++ni) sA[ni] = *(const bf16x8*)(wp[ni] + KH);
  KSTEP(0,  sA, sB, true,  KH)
  KSTEP(1,  sB, sA, true,  KH)
  KSTEP(2,  sA, sB, true,  KH)
  KSTEP(3,  sB, sA, true,  KH)
  KSTEP(4,  sA, sB, true,  KH)
  KSTEP(5,  sB, sA, true,  KH)
  KSTEP(6,  sA, sB, true,  KH)
  KSTEP(7,  sB, sA, true,  KH)
  KSTEP(8,  sA, sB, true,  KH)
  KSTEP(9,  sB, sA, true,  KH)
  KSTEP(10, sA, sB, false, KH)
#undef KSTEP
#undef STAGE_HALF

  // ---- epilogue: C/D layout col = lr -> u, row = lg*4 + j -> m
  #pragma unroll
  for (int ni = 0; ni < 3; ++ni) {
    const int u = u0 + ni * 16 + lr;
    if (u >= Tdim) continue;           // pad u-rows (>=720) skipped
    const float bias = beff[u];
    #pragma unroll
    for (int mi = 0; mi < 4; ++mi) {
      const int mb = m0 + mi * 16 + lg * 4;
      #pragma unroll
      for (int j = 0; j < 4; ++j)
        out[(size_t)(mb + j) * Tdim + u] = acc[mi][ni][j] + bias;
    }
  }
}

extern "C" void kernel_launch(void* const* d_in, const int* in_sizes, int n_in,
                              void* d_out, int out_size, void* d_ws, size_t ws_size,
                              hipStream_t stream) {
  const float* x  = (const float*)d_in[0];
  const float* tw = (const float*)d_in[1];
  const float* tb = (const float*)d_in[2];
  const float* sw = (const float*)d_in[3];
  const float* sb = (const float*)d_in[4];
  float* out = (float*)d_out;

  __bf16* Wb  = (__bf16*)d_ws;
  float* beff = (float*)((char*)d_ws + (size_t)WROWS * KP * sizeof(__bf16));

  const int fold_total = WROWS * KP;
  fold_w_kernel<<<dim3((fold_total + 255) / 256), dim3(256), 0, stream>>>(
      tw, tb, sw, sb, Wb, beff);

  const int M = in_sizes[0] / Tdim;            // 16384
  dim3 grid((M / BM) * 2);                     // 512 blocks: (m-tile, n-half)
  dlinear_gemm<<<grid, dim3(512), 0, stream>>>(x, Wb, beff, out);
}

// Round 15
// 49.032 us; speedup vs baseline: 1.0462x; 1.0462x over previous
//
#include <hip/hip_runtime.h>
#include <hip/hip_bf16.h>

// out[m,u] = sum_t x[m,t] * W_eff[u,t] + b_eff[u]      (m = 32*512 rows)
//   W_eff = Ws + (Wt - Ws) @ A   (A = causal window-mean, window 25)
// Round-15: r13 base (512 thr / 8 waves, BM=64, x-tile in LDS, ONE barrier,
// depth-2 W ring, zero-barrier K-loop) + N-GROUP STORE INTERLEAVE:
// wave's 6 n-frags -> 2 groups of 3; K(g0) -> issue stores(g0) -> K(g1)
// -> stores(g1). Group-0 store drain overlaps group-1's L2-bound K-loop.
// W t0/t1 prefetch hoisted above x-staging (rides under prologue latency).

#define Tdim  720
#define KP    736      // padded K (23*32); Wb zero-filled for k>=720
#define WROWS 768      // padded u-rows of Wb (zero rows >=720)
#define BM    64
#define APAD  740      // LDS row stride: 370 dw, %32=18 -> ~2-way banks (r13)

using bf16x8 = __attribute__((ext_vector_type(8))) __bf16;
using f32x4  = __attribute__((ext_vector_type(4))) float;

__global__ void fold_w_kernel(const float* __restrict__ tw,
                              const float* __restrict__ tb,
                              const float* __restrict__ sw,
                              const float* __restrict__ sb,
                              __bf16* __restrict__ Wb,
                              float* __restrict__ beff) {
  int idx = blockIdx.x * 256 + threadIdx.x;
  if (idx >= WROWS * KP) return;
  int u = idx / KP;
  int i = idx - u * KP;
  float w = 0.0f;
  if (u < Tdim && i < Tdim) {
    const float* twr = tw + (size_t)u * Tdim;
    const float* swr = sw + (size_t)u * Tdim;
    int tend = (i + 25 < Tdim) ? (i + 25) : Tdim;
    float acc = 0.0f;
    if (i >= 24) {
      #pragma unroll 5
      for (int t = i; t < tend; ++t) acc += twr[t] - swr[t];
      acc *= 0.04f;
    } else {
      for (int t = i; t < tend; ++t) {
        float c = (t >= 24) ? 0.04f : 1.0f / (float)(t + 1);
        acc += (twr[t] - swr[t]) * c;
      }
    }
    w = swr[i] + acc;
  }
  Wb[idx] = (__bf16)w;
  if (i == 0 && u < Tdim) beff[u] = tb[u] + sb[u];
}

__global__ __launch_bounds__(512, 2)
void dlinear_gemm(const float* __restrict__ x,
                  const __bf16* __restrict__ Wb,
                  const float* __restrict__ beff,
                  float* __restrict__ out) {
  __shared__ __bf16 As[BM * APAD];   // 94720 B -> 1 block/CU

  const int tid  = threadIdx.x;
  const int lane = tid & 63;
  const int wid  = tid >> 6;          // 0..7
  const int lg = lane >> 4, lr = lane & 15;

  const int m0 = blockIdx.x * BM;
  const int u0 = wid * 96;            // wave owns 96 u-cols (768 = 8*96 padded)

  // ---- W stream pointers (all 6 frags; group g uses wp[3g..3g+2])
  const __bf16* wp[6];
  #pragma unroll
  for (int ni = 0; ni < 6; ++ni)
    wp[ni] = Wb + (size_t)(u0 + ni * 16 + lr) * KP + lg * 8;

  // depth-2 ring slots (3 frags each)
  bf16x8 s0[3], s1[3], s2[3];
  // hoist group-0 t0/t1 W loads ABOVE x staging (overlap prologue latency)
  #pragma unroll
  for (int ni = 0; ni < 3; ++ni) s0[ni] = *(const bf16x8*)(wp[ni]);
  #pragma unroll
  for (int ni = 0; ni < 3; ++ni) s1[ni] = *(const bf16x8*)(wp[ni] + 32);

  // ---- prologue: x[m0..m0+64) x [0..720) -> LDS bf16 (coalesced 32B/lane)
  #pragma unroll
  for (int c = 0; c < 12; ++c) {
    int idx = tid + 512 * c;          // 8-f32 chunk id; 90 chunks per row
    if (idx < BM * 90) {
      int row  = idx / 90;
      int col8 = idx - row * 90;
      const float* p = x + (size_t)(m0 + row) * Tdim + col8 * 8;
      f32x4 a0 = ((const f32x4*)p)[0];
      f32x4 a1 = ((const f32x4*)p)[1];
      bf16x8 v;
      #pragma unroll
      for (int j = 0; j < 4; ++j) { v[j] = (__bf16)a0[j]; v[j + 4] = (__bf16)a1[j]; }
      *(bf16x8*)(&As[row * APAD + col8 * 8]) = v;
    }
  }
  {  // zero the K-pad [720,736): 64 rows x 16 elems, 2 elems per thread
    int r = tid >> 3;
    int c = 720 + (tid & 7) * 2;
    As[r * APAD + c]     = (__bf16)0.0f;
    As[r * APAD + c + 1] = (__bf16)0.0f;
  }
  __syncthreads();                    // the ONLY barrier

  int arofs[4];
  #pragma unroll
  for (int mi = 0; mi < 4; ++mi) arofs[mi] = (mi * 16 + lr) * APAD + lg * 8;

  f32x4 acc[4][3];

#define GEMM_STEP(T, GB, SLOT, ISSUE_SLOT, DO_ISSUE)                           \
  {                                                                            \
    if (DO_ISSUE) {                                                            \
      _Pragma("unroll")                                                        \
      for (int ni = 0; ni < 3; ++ni)                                           \
        ISSUE_SLOT[ni] = *(const bf16x8*)(wp[(GB) + ni] + ((T) + 2) * 32);     \
    }                                                                          \
    bf16x8 av[4];                                                              \
    _Pragma("unroll")                                                          \
    for (int mi = 0; mi < 4; ++mi)                                             \
      av[mi] = *(const bf16x8*)(&As[arofs[mi] + (T) * 32]);                    \
    _Pragma("unroll")                                                          \
    for (int mi = 0; mi < 4; ++mi)                                             \
      _Pragma("unroll")                                                        \
      for (int ni = 0; ni < 3; ++ni)                                           \
        acc[mi][ni] = __builtin_amdgcn_mfma_f32_16x16x32_bf16(av[mi],          \
                        SLOT[ni], acc[mi][ni], 0, 0, 0);                       \
  }

#define KLOOP(GB)                                                              \
  for (int t = 0; t < 21; t += 3) {                                            \
    GEMM_STEP(t,     GB, s0, s2, true)                                         \
    GEMM_STEP(t + 1, GB, s1, s0, true)                                         \
    GEMM_STEP(t + 2, GB, s2, s1, true)                                         \
  }                                                                            \
  GEMM_STEP(21, GB, s0, s2, false)                                             \
  GEMM_STEP(22, GB, s1, s2, false)

#define STORE_GROUP(GB)                                                        \
  {                                                                            \
    _Pragma("unroll")                                                          \
    for (int ni = 0; ni < 3; ++ni) {                                           \
      const int u = u0 + ((GB) + ni) * 16 + lr;                                \
      if (u < Tdim) {                                                          \
        const float bias = beff[u];                                            \
        _Pragma("unroll")                                                      \
        for (int mi = 0; mi < 4; ++mi) {                                       \
          const int mb = m0 + mi * 16 + lg * 4;                                \
          _Pragma("unroll")                                                    \
          for (int j = 0; j < 4; ++j)                                          \
            out[(size_t)(mb + j) * Tdim + u] = acc[mi][ni][j] + bias;          \
        }                                                                      \
      }                                                                        \
    }                                                                          \
  }

  // ================= pass 0: n-group 0 (u0 .. u0+47) =================
  #pragma unroll
  for (int mi = 0; mi < 4; ++mi)
    #pragma unroll
    for (int ni = 0; ni < 3; ++ni) {
      f32x4 z; z[0] = 0.f; z[1] = 0.f; z[2] = 0.f; z[3] = 0.f;
      acc[mi][ni] = z;
    }
  KLOOP(0)

  // prefetch group-1 t0/t1 BEFORE the group-0 stores (overlap store drain)
  bf16x8 n0a[3], n1a[3];
  #pragma unroll
  for (int ni = 0; ni < 3; ++ni) n0a[ni] = *(const bf16x8*)(wp[3 + ni]);
  #pragma unroll
  for (int ni = 0; ni < 3; ++ni) n1a[ni] = *(const bf16x8*)(wp[3 + ni] + 32);

  STORE_GROUP(0)                      // stores drain under pass-1 K-loop

  // ================= pass 1: n-group 1 (u0+48 .. u0+95) ==============
  #pragma unroll
  for (int mi = 0; mi < 4; ++mi)
    #pragma unroll
    for (int ni = 0; ni < 3; ++ni) {
      f32x4 z; z[0] = 0.f; z[1] = 0.f; z[2] = 0.f; z[3] = 0.f;
      acc[mi][ni] = z;
    }
  #pragma unroll
  for (int ni = 0; ni < 3; ++ni) s0[ni] = n0a[ni];
  #pragma unroll
  for (int ni = 0; ni < 3; ++ni) s1[ni] = n1a[ni];
  KLOOP(3)
  STORE_GROUP(3)

#undef GEMM_STEP
#undef KLOOP
#undef STORE_GROUP
}

extern "C" void kernel_launch(void* const* d_in, const int* in_sizes, int n_in,
                              void* d_out, int out_size, void* d_ws, size_t ws_size,
                              hipStream_t stream) {
  const float* x  = (const float*)d_in[0];
  const float* tw = (const float*)d_in[1];
  const float* tb = (const float*)d_in[2];
  const float* sw = (const float*)d_in[3];
  const float* sb = (const float*)d_in[4];
  float* out = (float*)d_out;

  __bf16* Wb  = (__bf16*)d_ws;
  float* beff = (float*)((char*)d_ws + (size_t)WROWS * KP * sizeof(__bf16));

  const int fold_total = WROWS * KP;
  fold_w_kernel<<<dim3((fold_total + 255) / 256), dim3(256), 0, stream>>>(
      tw, tb, sw, sb, Wb, beff);

  const int M = in_sizes[0] / Tdim;            // 16384
  dim3 grid(M / BM);                           // 256 blocks, 1 per CU
  dlinear_gemm<<<grid, dim3(512), 0, stream>>>(x, Wb, beff, out);
}